// Round 7
// baseline (1725.057 us; speedup 1.0000x reference)
//
#include <hip/hip_runtime.h>

typedef _Float16 half_t;
typedef __attribute__((ext_vector_type(2))) _Float16 half2_t;

#define HROW 136   // padded LDS row stride (halves): 272B = 17*16B, 16B-aligned, bank phase 4/row

__device__ __forceinline__ half2_t bc2(unsigned int u){ return __builtin_bit_cast(half2_t, u); }
__device__ __forceinline__ float fdot2f(half2_t a, half2_t b, float c){
  return __builtin_amdgcn_fdot2(a, b, c, false);
}
__device__ __forceinline__ float rcp_f(float x){ return __builtin_amdgcn_rcpf(x); }
__device__ __forceinline__ float sigmoidf_(float x){ return rcp_f(1.0f+__expf(-x)); }
__device__ __forceinline__ float tanhf_(float x){ return 1.0f - 2.0f*rcp_f(__expf(2.0f*x)+1.0f); }

__device__ __forceinline__ void bar(){
  asm volatile("s_waitcnt lgkmcnt(0)\n\ts_barrier" ::: "memory");
}
__device__ __forceinline__ float red8(float v){
  v += __shfl_xor(v,1); v += __shfl_xor(v,2); v += __shfl_xor(v,4); return v;
}
// 16-half dot: two weight uint4 vs two x uint4 (8 fdot2, 2 chains)
__device__ __forceinline__ float dot16h(const uint4& w0, const uint4& w1,
                                        const uint4& x0, const uint4& x1){
  float a=0.f,b=0.f;
  a=fdot2f(bc2(w0.x),bc2(x0.x),a); b=fdot2f(bc2(w0.y),bc2(x0.y),b);
  a=fdot2f(bc2(w0.z),bc2(x0.z),a); b=fdot2f(bc2(w0.w),bc2(x0.w),b);
  a=fdot2f(bc2(w1.x),bc2(x1.x),a); b=fdot2f(bc2(w1.y),bc2(x1.y),b);
  a=fdot2f(bc2(w1.z),bc2(x1.z),a); b=fdot2f(bc2(w1.w),bc2(x1.w),b);
  return a+b;
}

// Pack f32 matrix (R x K slice at coloff, row stride ld) -> f16 [K/8][RT][8] at row_off.
__global__ void pack_k(const float* __restrict__ src, half_t* __restrict__ dst,
                       int R, int K, int ld, int coloff, int RT, int row_off){
  int idx = blockIdx.x*blockDim.x + threadIdx.x;
  if (idx >= R*K) return;
  int r = idx / K, k = idx - r*K;
  int kc = k >> 3, j = k & 7;
  dst[((size_t)kc*RT + row_off + r)*8 + j] = (half_t)src[(size_t)r*ld + coloff + k];
}

__global__ void __launch_bounds__(1024)
gru_main(
    const float* __restrict__ received,
    const float* __restrict__ Wih0d0, const float* __restrict__ Wih0d1,
    const float* __restrict__ bx0d0, const float* __restrict__ bh0d0,
    const float* __restrict__ bx1d0, const float* __restrict__ bh1d0,
    const float* __restrict__ bx0d1, const float* __restrict__ bh0d1,
    const float* __restrict__ bx1d1, const float* __restrict__ bh1d1,
    const float* __restrict__ vW, const float* __restrict__ fc2b,
    const half_t* __restrict__ W0pack, const half_t* __restrict__ W1pack,
    const half_t* __restrict__ WsPack, const half_t* __restrict__ WhPack,
    const half_t* __restrict__ fc2Pack,
    half_t* __restrict__ o1h, half_t* __restrict__ o2h)
{
  const int dec = blockIdx.x >> 5;
  const int b   = blockIdx.x & 31;
  const int tid = threadIdx.x;
  const int s   = tid & 7;     // k-segment lane (8-way split, 16 halves each)
  const int oct = tid >> 3;    // 128 octets

  const float* bx0  = dec ? bx0d1 : bx0d0;
  const float* bh0  = dec ? bh0d1 : bh0d0;
  const float* bx1  = dec ? bx1d1 : bx1d0;
  const float* bh1  = dec ? bh1d1 : bh1d0;
  const float* Wih0 = dec ? Wih0d1 : Wih0d0;
  const half_t* W0  = W0pack + (size_t)dec*49152;   // [16][384][8]  Whh0
  const half_t* W1  = W1pack + (size_t)dec*98304;   // [16][768][8]  rows 0-383 Wih1, 384-767 Whh1
  half_t* od = dec ? o2h : o1h;

  __shared__ __align__(16) half_t sh_hist[2][128*HROW];    // raw h history (padded rows)
  __shared__ __align__(16) half_t sh_histWh[2][128*HROW];  // hist @ Wh.T (padded rows)
  __shared__ __align__(16) float  sh_gx[384];
  __shared__ __align__(16) float  sh_gh[384];
  __shared__ __align__(16) float  sh_g1x[384];
  __shared__ __align__(16) float  sh_g1h[384];
  __shared__ __align__(16) float  sh_sWs[2][128];
  __shared__ __align__(16) float  sh_logits[2][128];
  __shared__ __align__(16) float  sh_probs[2][128];
  __shared__ __align__(16) float  sh_hatt[2][128];
  __shared__ __align__(16) half_t sh_hatt_pk[2][128];
  __shared__ __align__(16) half_t sh_hraw_pk[2][128];
  __shared__ __align__(16) half_t sh_fc2in[2][256];        // [c | h_raw]
  __shared__ __align__(16) float  sh_x[2][4];
  __shared__ __align__(16) float  sh_vW[128];
  __shared__ __align__(16) float4 sh_Wx4[384];             // Wih0 3 cols + bias

  // ---------- resident weights: 26 uint4 = 104 VGPRs ----------
  uint4 wA[12];  // P1: 6 rows (3 Whh0 @ oct+128n, 3 Whh1 @ oct+128n), k-seg [16s,16s+16)
  #pragma unroll
  for (int n=0;n<3;++n)
    #pragma unroll
    for (int c=0;c<2;++c)
      wA[2*n+c] = *reinterpret_cast<const uint4*>(W0 + ((size_t)(2*s+c)*384 + oct + 128*n)*8);
  #pragma unroll
  for (int n=0;n<3;++n)
    #pragma unroll
    for (int c=0;c<2;++c)
      wA[6+2*n+c] = *reinterpret_cast<const uint4*>(W1 + ((size_t)(2*s+c)*768 + 384 + oct + 128*n)*8);
  uint4 wC[6];   // P3: 3 rows of Wih1 @ oct+128n
  #pragma unroll
  for (int n=0;n<3;++n)
    #pragma unroll
    for (int c=0;c<2;++c)
      wC[2*n+c] = *reinterpret_cast<const uint4*>(W1 + ((size_t)(2*s+c)*768 + oct + 128*n)*8);
  uint4 wS0 = *reinterpret_cast<const uint4*>(WsPack + ((size_t)(2*s  )*128 + oct)*8);
  uint4 wS1 = *reinterpret_cast<const uint4*>(WsPack + ((size_t)(2*s+1)*128 + oct)*8);
  uint4 wH0 = *reinterpret_cast<const uint4*>(WhPack + ((size_t)(2*s  )*128 + oct)*8);
  uint4 wH1 = *reinterpret_cast<const uint4*>(WhPack + ((size_t)(2*s+1)*128 + oct)*8);
  uint4 wF[4];   // P9: fc2 row oct, k-seg [32s,32s+32)
  #pragma unroll
  for (int c=0;c<4;++c)
    wF[c] = *reinterpret_cast<const uint4*>(fc2Pack + ((size_t)(4*s+c)*128 + oct)*8);

  float biasW = 0.f;
  if (s < 3)      biasW = bh0[oct + 128*s];
  else if (s < 6) biasW = bh1[oct + 128*(s-3)];
  const float biasC = (s < 3) ? bx1[oct + 128*s] : 0.f;
  const float bF = fc2b[oct];

  // ---------- LDS init ----------
  if (tid < 256){ int l=tid>>7, r=tid&127; sh_hatt[l][r]=0.f; sh_hatt_pk[l][r]=(half_t)0.f; }
  if (tid < 128) sh_vW[tid] = vW[tid];
  if (tid < 384) sh_Wx4[tid] = make_float4(Wih0[tid*3], Wih0[tid*3+1], Wih0[tid*3+2], bx0[tid]);
  if (tid < 3)   sh_x[0][tid] = received[(b*128)*3 + tid];
  bar();

  for (int i=0; i<128; ++i){
    // ---- P1: gh0 = Whh0@hatt0 ; g1h = Whh1@hatt1 ; gx0 ----
    {
      uint4 xa0 = *reinterpret_cast<const uint4*>(&sh_hatt_pk[0][16*s]);
      uint4 xa1 = *reinterpret_cast<const uint4*>(&sh_hatt_pk[0][16*s+8]);
      float r0 = red8(dot16h(wA[0],wA[1],xa0,xa1));
      float r1 = red8(dot16h(wA[2],wA[3],xa0,xa1));
      float r2 = red8(dot16h(wA[4],wA[5],xa0,xa1));
      uint4 xb0 = *reinterpret_cast<const uint4*>(&sh_hatt_pk[1][16*s]);
      uint4 xb1 = *reinterpret_cast<const uint4*>(&sh_hatt_pk[1][16*s+8]);
      float r3 = red8(dot16h(wA[6],wA[7],xb0,xb1));
      float r4 = red8(dot16h(wA[8],wA[9],xb0,xb1));
      float r5 = red8(dot16h(wA[10],wA[11],xb0,xb1));
      if      (s==0) sh_gh[oct]      = r0 + biasW;
      else if (s==1) sh_gh[oct+128]  = r1 + biasW;
      else if (s==2) sh_gh[oct+256]  = r2 + biasW;
      else if (s==3) sh_g1h[oct]     = r3 + biasW;
      else if (s==4) sh_g1h[oct+128] = r4 + biasW;
      else if (s==5) sh_g1h[oct+256] = r5 + biasW;
      if (tid < 384){
        float4 wx = sh_Wx4[tid];
        float xv0=sh_x[i&1][0], xv1=sh_x[i&1][1], xv2=sh_x[i&1][2];
        sh_gx[tid] = wx.w + wx.x*xv0 + wx.y*xv1 + wx.z*xv2;
      }
    }
    bar();
    // ---- P2: layer0 cell ----
    if (tid < 128){
      float rr = sigmoidf_(sh_gx[tid]+sh_gh[tid]);
      float zz = sigmoidf_(sh_gx[128+tid]+sh_gh[128+tid]);
      float nn = tanhf_(sh_gx[256+tid] + rr*sh_gh[256+tid]);
      float h0 = (1.f-zz)*nn + zz*sh_hatt[0][tid];
      half_t hh=(half_t)h0;
      sh_hist[0][i*HROW+tid]=hh;
      sh_hraw_pk[0][tid]=hh; sh_fc2in[0][128+tid]=hh;
    }
    bar();
    // ---- P3: g1x = Wih1 @ h0_raw ----
    {
      uint4 x0 = *reinterpret_cast<const uint4*>(&sh_hraw_pk[0][16*s]);
      uint4 x1 = *reinterpret_cast<const uint4*>(&sh_hraw_pk[0][16*s+8]);
      float r0 = red8(dot16h(wC[0],wC[1],x0,x1));
      float r1 = red8(dot16h(wC[2],wC[3],x0,x1));
      float r2 = red8(dot16h(wC[4],wC[5],x0,x1));
      if      (s==0) sh_g1x[oct]     = r0 + biasC;
      else if (s==1) sh_g1x[oct+128] = r1 + biasC;
      else if (s==2) sh_g1x[oct+256] = r2 + biasC;
    }
    bar();
    // ---- P4: layer1 cell + raw output ----
    if (tid < 128){
      float rr = sigmoidf_(sh_g1x[tid]+sh_g1h[tid]);
      float zz = sigmoidf_(sh_g1x[128+tid]+sh_g1h[128+tid]);
      float nn = tanhf_(sh_g1x[256+tid] + rr*sh_g1h[256+tid]);
      float h1 = (1.f-zz)*nn + zz*sh_hatt[1][tid];
      half_t hh=(half_t)h1;
      sh_hist[1][i*HROW+tid]=hh;
      sh_hraw_pk[1][tid]=hh; sh_fc2in[1][128+tid]=hh;
      od[(size_t)(b*128+i)*128 + tid] = hh;
    }
    bar();
    // ---- P5: sWs[l] = Ws@h_raw[l]; histWh[l][i] = Wh@h_raw[l] (resident Ws/Wh) ----
    {
      uint4 x0 = *reinterpret_cast<const uint4*>(&sh_hraw_pk[0][16*s]);
      uint4 x1 = *reinterpret_cast<const uint4*>(&sh_hraw_pk[0][16*s+8]);
      float s0v = red8(dot16h(wS0,wS1,x0,x1));
      float h0v = red8(dot16h(wH0,wH1,x0,x1));
      uint4 y0 = *reinterpret_cast<const uint4*>(&sh_hraw_pk[1][16*s]);
      uint4 y1 = *reinterpret_cast<const uint4*>(&sh_hraw_pk[1][16*s+8]);
      float s1v = red8(dot16h(wS0,wS1,y0,y1));
      float h1v = red8(dot16h(wH0,wH1,y0,y1));
      if (s==0){
        sh_sWs[0][oct]=s0v; sh_sWs[1][oct]=s1v;
        sh_histWh[0][i*HROW+oct]=(half_t)h0v;
        sh_histWh[1][i*HROW+oct]=(half_t)h1v;
      }
      if (tid<3 && i<127) sh_x[(i+1)&1][tid] = received[(b*128+i+1)*3+tid];
    }
    bar();
    if (i > 0){
      // ---- P6: logits, 4 lanes per (l,t), 32 elems each ----
      {
        int q=tid&3, t=(tid>>2)&127, l=tid>>9;
        float sacc=0.f;
        if (t<=i){
          const half_t* hwp = &sh_histWh[l][t*HROW + 32*q];
          const float* sw = &sh_sWs[l][32*q];
          const float* vv = &sh_vW[32*q];
          #pragma unroll
          for (int jb=0;jb<4;++jb){
            uint4 h = *reinterpret_cast<const uint4*>(hwp + 8*jb);
            float4 sv0 = *reinterpret_cast<const float4*>(sw + 8*jb);
            float4 sv1 = *reinterpret_cast<const float4*>(sw + 8*jb + 4);
            float4 vf0 = *reinterpret_cast<const float4*>(vv + 8*jb);
            float4 vf1 = *reinterpret_cast<const float4*>(vv + 8*jb + 4);
            half2_t p0=bc2(h.x), p1=bc2(h.y), p2=bc2(h.z), p3=bc2(h.w);
            sacc += tanhf_(sv0.x+(float)p0[0])*vf0.x;
            sacc += tanhf_(sv0.y+(float)p0[1])*vf0.y;
            sacc += tanhf_(sv0.z+(float)p1[0])*vf0.z;
            sacc += tanhf_(sv0.w+(float)p1[1])*vf0.w;
            sacc += tanhf_(sv1.x+(float)p2[0])*vf1.x;
            sacc += tanhf_(sv1.y+(float)p2[1])*vf1.y;
            sacc += tanhf_(sv1.z+(float)p3[0])*vf1.z;
            sacc += tanhf_(sv1.w+(float)p3[1])*vf1.w;
          }
        }
        sacc += __shfl_xor(sacc,1); sacc += __shfl_xor(sacc,2);
        if ((tid&3)==0 && t<=i) sh_logits[l][t]=sacc;
      }
      bar();
      // ---- P7: masked softmax (|logit| <= sum|v| ~ 6, no max-sub) ----
      if (tid < 128){
        int l=tid>>6, lane=tid&63;
        float p0 = (lane<=i)    ? __expf(sh_logits[l][lane])    : 0.f;
        float p1 = (lane+64<=i) ? __expf(sh_logits[l][lane+64]) : 0.f;
        float ss = p0+p1;
        #pragma unroll
        for (int k=1;k<64;k<<=1) ss += __shfl_xor(ss,k);
        float inv = rcp_f(ss);
        sh_probs[l][lane]=p0*inv; sh_probs[l][lane+64]=p1*inv;
      }
      bar();
      // ---- P8: context, 8 lanes per (l, col-pair) ----
      {
        int s8=tid&7, o2=(tid>>3)&63, l=tid>>9;
        float c0=0.f,c1=0.f;
        #pragma unroll
        for (int c=0;c<16;++c){
          int t = s8 + 8*c;
          if (t<=i){
            float a = sh_probs[l][t];
            half2_t h2 = *reinterpret_cast<const half2_t*>(&sh_hist[l][t*HROW + 2*o2]);
            c0 += a*(float)h2[0]; c1 += a*(float)h2[1];
          }
        }
        c0 = red8(c0); c1 = red8(c1);
        if (s8==0){
          sh_fc2in[l][2*o2]   = (half_t)c0;
          sh_fc2in[l][2*o2+1] = (half_t)c1;
        }
      }
      bar();
      // ---- P9: h_att[l] = fc2 @ [c|h_raw] + fc2_b (resident fc2) ----
      {
        uint4 a0=*reinterpret_cast<const uint4*>(&sh_fc2in[0][32*s]);
        uint4 a1=*reinterpret_cast<const uint4*>(&sh_fc2in[0][32*s+8]);
        uint4 a2=*reinterpret_cast<const uint4*>(&sh_fc2in[0][32*s+16]);
        uint4 a3=*reinterpret_cast<const uint4*>(&sh_fc2in[0][32*s+24]);
        float e0 = red8(dot16h(wF[0],wF[1],a0,a1) + dot16h(wF[2],wF[3],a2,a3));
        uint4 b0=*reinterpret_cast<const uint4*>(&sh_fc2in[1][32*s]);
        uint4 b1=*reinterpret_cast<const uint4*>(&sh_fc2in[1][32*s+8]);
        uint4 b2=*reinterpret_cast<const uint4*>(&sh_fc2in[1][32*s+16]);
        uint4 b3=*reinterpret_cast<const uint4*>(&sh_fc2in[1][32*s+24]);
        float e1 = red8(dot16h(wF[0],wF[1],b0,b1) + dot16h(wF[2],wF[3],b2,b3));
        if (s==0){
          float v0=e0+bF; sh_hatt[0][oct]=v0; sh_hatt_pk[0][oct]=(half_t)v0;
          float v1=e1+bF; sh_hatt[1][oct]=v1; sh_hatt_pk[1][oct]=(half_t)v1;
        }
      }
    } else {
      if (tid < 256){
        int l=tid>>7, row=tid&127;
        half_t hv = sh_hraw_pk[l][row];
        sh_hatt[l][row]=(float)hv; sh_hatt_pk[l][row]=hv;
      }
    }
    bar();
  }
}

// Final: out[b,t] = sigmoid(tanh(out_W . [o1[b,t] | o2[b,min(t+10,127)]] + out_b))
__global__ void out_kernel(const half_t* __restrict__ o1h, const half_t* __restrict__ o2h,
                           const float* __restrict__ outW, const float* __restrict__ outb,
                           float* __restrict__ dout){
  int tid = blockIdx.x*blockDim.x + threadIdx.x;
  int q = tid&3, job = tid>>2;
  int b = job>>7, t = job&127;
  int t2 = t+10; if (t2>127) t2=127;
  const half_t* r1 = o1h + (size_t)(b*128+t)*128;
  const half_t* r2 = o2h + (size_t)(b*128+t2)*128;
  float acc=0.f;
  for (int j=q*32; j<q*32+32; ++j) acc += outW[j]*(float)r1[j];
  for (int j=q*32; j<q*32+32; ++j) acc += outW[128+j]*(float)r2[j];
  acc += __shfl_xor(acc,1);
  acc += __shfl_xor(acc,2);
  if (q==0){
    float d = tanhf_(acc + outb[0]);
    dout[job] = rcp_f(1.f+__expf(-d));
  }
}

static inline void launch_pack(const void* src, half_t* dst, int R, int K, int ld,
                               int coloff, int RT, int row_off, hipStream_t s){
  int total = R*K;
  pack_k<<<(total+255)/256, 256, 0, s>>>((const float*)src, dst, R, K, ld, coloff, RT, row_off);
}

extern "C" void kernel_launch(void* const* d_in, const int* in_sizes, int n_in,
                              void* d_out, int out_size, void* d_ws, size_t ws_size,
                              hipStream_t stream) {
  const float* received = (const float*)d_in[0];
  const float* Wih1_0 = (const float*)d_in[1];
  const float* Whh1_0 = (const float*)d_in[2];
  const float* bih1_0 = (const float*)d_in[3];
  const float* bhh1_0 = (const float*)d_in[4];
  const float* Wih1_1 = (const float*)d_in[5];
  const float* Whh1_1 = (const float*)d_in[6];
  const float* bih1_1 = (const float*)d_in[7];
  const float* bhh1_1 = (const float*)d_in[8];
  const float* Wih2_0 = (const float*)d_in[9];
  const float* Whh2_0 = (const float*)d_in[10];
  const float* bih2_0 = (const float*)d_in[11];
  const float* bhh2_0 = (const float*)d_in[12];
  const float* Wih2_1 = (const float*)d_in[13];
  const float* Whh2_1 = (const float*)d_in[14];
  const float* bih2_1 = (const float*)d_in[15];
  const float* bhh2_1 = (const float*)d_in[16];
  const float* attn_W = (const float*)d_in[17];
  const float* v_W    = (const float*)d_in[18];
  const float* fc2_W  = (const float*)d_in[19];
  const float* fc2_b  = (const float*)d_in[20];
  const float* out_W  = (const float*)d_in[21];
  const float* out_b  = (const float*)d_in[22];

  half_t* ws = (half_t*)d_ws;
  half_t* W0pack  = ws + 0;        // 2 x [16][384][8] = 98304
  half_t* W1pack  = ws + 98304;    // 2 x [16][768][8] = 196608
  half_t* WsPack  = ws + 294912;   // [16][128][8] = 16384
  half_t* WhPack  = ws + 311296;   // 16384
  half_t* fc2Pack = ws + 327552;   // [32][128][8] = 32768
  half_t* o1h     = ws + 360448;   // 32*128*128 = 524288
  half_t* o2h     = ws + 884736;   // 524288

  launch_pack(Whh1_0, W0pack,          384, 128, 128, 0, 384, 0, stream);
  launch_pack(Whh2_0, W0pack + 49152,  384, 128, 128, 0, 384, 0, stream);
  launch_pack(Wih1_1, W1pack,          384, 128, 128, 0, 768, 0, stream);
  launch_pack(Whh1_1, W1pack,          384, 128, 128, 0, 768, 384, stream);
  launch_pack(Wih2_1, W1pack + 98304,  384, 128, 128, 0, 768, 0, stream);
  launch_pack(Whh2_1, W1pack + 98304,  384, 128, 128, 0, 768, 384, stream);
  launch_pack(attn_W, WsPack,          128, 128, 256, 0,   128, 0, stream);
  launch_pack(attn_W, WhPack,          128, 128, 256, 128, 128, 0, stream);
  launch_pack(fc2_W,  fc2Pack,         128, 256, 256, 0,   128, 0, stream);

  gru_main<<<64, 1024, 0, stream>>>(
      received,
      Wih1_0, Wih2_0,
      bih1_0, bhh1_0, bih1_1, bhh1_1,
      bih2_0, bhh2_0, bih2_1, bhh2_1,
      v_W, fc2_b,
      W0pack, W1pack, WsPack, WhPack, fc2Pack,
      o1h, o2h);

  out_kernel<<<64, 256, 0, stream>>>(o1h, o2h, out_W, out_b, (float*)d_out);
}

// Round 8
// 1562.266 us; speedup vs baseline: 1.1042x; 1.1042x over previous
//
#include <hip/hip_runtime.h>

typedef _Float16 half_t;
typedef __attribute__((ext_vector_type(2))) _Float16 half2_t;

__device__ __forceinline__ half2_t bc2(unsigned int u){ return __builtin_bit_cast(half2_t, u); }
__device__ __forceinline__ int   bcI(half2_t v){ return __builtin_bit_cast(int, v); }
__device__ __forceinline__ half2_t bcH(int v){ return __builtin_bit_cast(half2_t, v); }
__device__ __forceinline__ float fdot2f(half2_t a, half2_t b, float c){
  return __builtin_amdgcn_fdot2(a, b, c, false);
}
__device__ __forceinline__ float rcp_f(float x){ return __builtin_amdgcn_rcpf(x); }
__device__ __forceinline__ float sigmoidf_(float x){ return rcp_f(1.0f+__expf(-x)); }
__device__ __forceinline__ float tanhf_(float x){ return 1.0f - 2.0f*rcp_f(__expf(2.0f*x)+1.0f); }

// DPP quad_perm cross-lane (VALU pipe, no LDS): xor1 = [1,0,3,2]=0xB1, xor2 = [2,3,0,1]=0x4E
__device__ __forceinline__ float qxor1(float v){
  return __builtin_bit_cast(float, __builtin_amdgcn_mov_dpp(__builtin_bit_cast(int,v),0xB1,0xF,0xF,true));
}
__device__ __forceinline__ float qxor2(float v){
  return __builtin_bit_cast(float, __builtin_amdgcn_mov_dpp(__builtin_bit_cast(int,v),0x4E,0xF,0xF,true));
}
__device__ __forceinline__ float qsum4(float v){ v += qxor1(v); v += qxor2(v); return v; }

// Barrier WITHOUT vmcnt drain (LDS ordering only)
__device__ __forceinline__ void bar(){
  asm volatile("s_waitcnt lgkmcnt(0)\n\ts_barrier" ::: "memory");
}

// 32-half dot: 4 w uint4 vs 4 x uint4 (16 fdot2, 4 chains)
__device__ __forceinline__ float dot32(const uint4* w, const uint4* x){
  float a=0.f,b=0.f,c=0.f,d=0.f;
  #pragma unroll
  for (int m=0;m<4;++m){
    a=fdot2f(bc2(w[m].x),bc2(x[m].x),a);
    b=fdot2f(bc2(w[m].y),bc2(x[m].y),b);
    c=fdot2f(bc2(w[m].z),bc2(x[m].z),c);
    d=fdot2f(bc2(w[m].w),bc2(x[m].w),d);
  }
  return (a+b)+(c+d);
}

// Pack f32 matrix (R x K slice at coloff, row stride ld) -> f16 [K/8][RT][8] at row_off.
__global__ void pack_k(const float* __restrict__ src, half_t* __restrict__ dst,
                       int R, int K, int ld, int coloff, int RT, int row_off){
  int idx = blockIdx.x*blockDim.x + threadIdx.x;
  if (idx >= R*K) return;
  int r = idx / K, k = idx - r*K;
  int kc = k >> 3, j = k & 7;
  dst[((size_t)kc*RT + row_off + r)*8 + j] = (half_t)src[(size_t)r*ld + coloff + k];
}

__launch_bounds__(512)
__global__ void gru_main(
    const float* __restrict__ received,
    const float* __restrict__ Wih0d0, const float* __restrict__ Wih0d1,
    const float* __restrict__ bx0d0, const float* __restrict__ bh0d0,
    const float* __restrict__ bx1d0, const float* __restrict__ bh1d0,
    const float* __restrict__ bx0d1, const float* __restrict__ bh0d1,
    const float* __restrict__ bx1d1, const float* __restrict__ bh1d1,
    const float* __restrict__ vW, const float* __restrict__ fc2b,
    const half_t* __restrict__ W0pack, const half_t* __restrict__ W1pack,
    const half_t* __restrict__ WsPack, const half_t* __restrict__ WhPack,
    const half_t* __restrict__ fc2Pack,
    half_t* __restrict__ o1h, half_t* __restrict__ o2h)
{
  const int dec = blockIdx.x >> 5;
  const int b   = blockIdx.x & 31;
  const int tid = threadIdx.x;
  const int q   = tid & 3;     // quad k-slice lane (32 halves each)
  const int r   = tid >> 2;    // 0..127 row id

  const float* bx0  = dec ? bx0d1 : bx0d0;
  const float* bh0  = dec ? bh0d1 : bh0d0;
  const float* bx1  = dec ? bx1d1 : bx1d0;
  const float* bh1  = dec ? bh1d1 : bh1d0;
  const float* Wih0 = dec ? Wih0d1 : Wih0d0;
  const half_t* W0  = W0pack + (size_t)dec*49152;   // [16][384][8]  Whh0
  const half_t* W1  = W1pack + (size_t)dec*98304;   // [16][768][8]  rows 0-383 Wih1, 384-767 Whh1
  half_t* od = dec ? o2h : o1h;

  // rows padded to 136 halves (272B): +16B per row rotates bank phase
  __shared__ __align__(16) half_t sh_hist[2][128*136];    // octet-swizzled by (t&15)
  __shared__ __align__(16) half_t sh_histWh[2][128*136];  // octet-swizzled by (t&15)
  __shared__ __align__(16) float  sh_gx[384];
  __shared__ __align__(16) float  sh_gh[384];
  __shared__ __align__(16) float  sh_g1x[384];
  __shared__ __align__(16) float  sh_g1h[384];
  __shared__ __align__(16) half_t sh_sWs16[2][128];
  __shared__ __align__(16) float  sh_probs[2][128];       // UNNORMALIZED exp(logit-4)
  __shared__ __align__(16) float  sh_hatt32[2][128];
  __shared__ __align__(16) half_t sh_hatt_pk[2][128];
  __shared__ __align__(16) float  sh_hraw32[2][128];
  __shared__ __align__(16) half_t sh_hraw_pk[2][128];
  __shared__ __align__(16) half_t sh_fc2in[2][256];       // [c | h_raw]
  __shared__ __align__(16) half_t sh_vW16[128];

  // ---- loop-invariant registers ----
  float bA=0.f,bB=0.f,bC=0.f;
  if (q==0){ bA=bh0[r];     bB=bh1[r+128]; bC=bx1[r];     }
  else if (q==1){ bA=bh0[r+128]; bB=bh1[r+256]; bC=bx1[r+128]; }
  else if (q==2){ bA=bh0[r+256];                bC=bx1[r+256]; }
  else { bB=bh1[r]; }
  const float bF = fc2b[r];
  float wx0=0.f,wx1=0.f,wx2=0.f,wxw=0.f;
  if (tid < 384){ wx0=Wih0[tid*3]; wx1=Wih0[tid*3+1]; wx2=Wih0[tid*3+2]; wxw=bx0[tid]; }

  // ---- LDS init ----
  {
    uint4 z = make_uint4(0u,0u,0u,0u);
    uint4* ph = reinterpret_cast<uint4*>(&sh_hist[0][0]);     // 2*128*136/8 = 4352 u4
    uint4* pw = reinterpret_cast<uint4*>(&sh_histWh[0][0]);
    for (int j=tid; j<4352; j+=512){ ph[j]=z; pw[j]=z; }
  }
  if (tid < 256){ int l=tid>>7, rr=tid&127; sh_hatt32[l][rr]=0.f; sh_hatt_pk[l][rr]=(half_t)0.f; }
  if (tid < 128) sh_vW16[tid] = (half_t)vW[tid];
  bar();

  for (int i=0; i<128; ++i){
    // ---- P1: gh0 = Whh0@hatt0 ; g1h = Whh1@hatt1 ; gx0 ----
    {
      uint4 xa[4];
      #pragma unroll
      for (int m=0;m<4;++m) xa[m] = *reinterpret_cast<const uint4*>(&sh_hatt_pk[0][32*q+8*m]);
      float a0,a1,a2;
      {
        uint4 w[12];
        #pragma unroll
        for (int n=0;n<3;++n)
          #pragma unroll
          for (int m=0;m<4;++m)
            w[4*n+m] = *reinterpret_cast<const uint4*>(W0 + ((size_t)(4*q+m)*384 + r + 128*n)*8);
        a0 = dot32(&w[0],xa); a1 = dot32(&w[4],xa); a2 = dot32(&w[8],xa);
      }
      uint4 xb[4];
      #pragma unroll
      for (int m=0;m<4;++m) xb[m] = *reinterpret_cast<const uint4*>(&sh_hatt_pk[1][32*q+8*m]);
      float a3,a4,a5;
      {
        uint4 w[12];
        #pragma unroll
        for (int n=0;n<3;++n)
          #pragma unroll
          for (int m=0;m<4;++m)
            w[4*n+m] = *reinterpret_cast<const uint4*>(W1 + ((size_t)(4*q+m)*768 + 384 + r + 128*n)*8);
        a3 = dot32(&w[0],xb); a4 = dot32(&w[4],xb); a5 = dot32(&w[8],xb);
      }
      a0=qsum4(a0); a1=qsum4(a1); a2=qsum4(a2);
      a3=qsum4(a3); a4=qsum4(a4); a5=qsum4(a5);
      if      (q==0){ sh_gh[r]      = a0+bA; sh_g1h[r+128] = a4+bB; }
      else if (q==1){ sh_gh[r+128]  = a1+bA; sh_g1h[r+256] = a5+bB; }
      else if (q==2){ sh_gh[r+256]  = a2+bA; }
      else          { sh_g1h[r]     = a3+bB; }
      if (tid < 384){
        const float* xr = &received[((size_t)b*128+i)*3];
        sh_gx[tid] = wxw + wx0*xr[0] + wx1*xr[1] + wx2*xr[2];
      }
    }
    bar();
    // ---- P2: layer0 cell ----
    if (tid < 128){
      float rr = sigmoidf_(sh_gx[tid]+sh_gh[tid]);
      float zz = sigmoidf_(sh_gx[128+tid]+sh_gh[128+tid]);
      float nn = tanhf_(sh_gx[256+tid] + rr*sh_gh[256+tid]);
      float h0 = (1.f-zz)*nn + zz*sh_hatt32[0][tid];
      sh_hraw32[0][tid]=h0;
      half_t hh=(half_t)h0;
      sh_hist[0][i*136 + ((tid>>3)^(i&15))*8 + (tid&7)] = hh;
      sh_hraw_pk[0][tid]=hh; sh_fc2in[0][128+tid]=hh;
    }
    bar();
    // ---- P3: g1x = Wih1 @ h0_raw ----
    {
      uint4 xc[4];
      #pragma unroll
      for (int m=0;m<4;++m) xc[m] = *reinterpret_cast<const uint4*>(&sh_hraw_pk[0][32*q+8*m]);
      uint4 w[12];
      #pragma unroll
      for (int n=0;n<3;++n)
        #pragma unroll
        for (int m=0;m<4;++m)
          w[4*n+m] = *reinterpret_cast<const uint4*>(W1 + ((size_t)(4*q+m)*768 + r + 128*n)*8);
      float a0 = dot32(&w[0],xc), a1 = dot32(&w[4],xc), a2 = dot32(&w[8],xc);
      a0=qsum4(a0); a1=qsum4(a1); a2=qsum4(a2);
      if      (q==0) sh_g1x[r]     = a0+bC;
      else if (q==1) sh_g1x[r+128] = a1+bC;
      else if (q==2) sh_g1x[r+256] = a2+bC;
    }
    bar();
    // ---- P4: layer1 cell + raw output ----
    if (tid < 128){
      float rr = sigmoidf_(sh_g1x[tid]+sh_g1h[tid]);
      float zz = sigmoidf_(sh_g1x[128+tid]+sh_g1h[128+tid]);
      float nn = tanhf_(sh_g1x[256+tid] + rr*sh_g1h[256+tid]);
      float h1 = (1.f-zz)*nn + zz*sh_hatt32[1][tid];
      sh_hraw32[1][tid]=h1;
      half_t hh=(half_t)h1;
      sh_hist[1][i*136 + ((tid>>3)^(i&15))*8 + (tid&7)] = hh;
      sh_hraw_pk[1][tid]=hh; sh_fc2in[1][128+tid]=hh;
      od[(size_t)(b*128+i)*128 + tid] = hh;
    }
    bar();
    // ---- P5: sWs[l]=Ws@h_raw[l] (f16), histWh[l][i]=Wh@h_raw[l] ----
    {
      uint4 xa[4], xb[4], ws[4], wh[4];
      #pragma unroll
      for (int m=0;m<4;++m){
        xa[m] = *reinterpret_cast<const uint4*>(&sh_hraw_pk[0][32*q+8*m]);
        xb[m] = *reinterpret_cast<const uint4*>(&sh_hraw_pk[1][32*q+8*m]);
        ws[m] = *reinterpret_cast<const uint4*>(WsPack + ((size_t)(4*q+m)*128 + r)*8);
        wh[m] = *reinterpret_cast<const uint4*>(WhPack + ((size_t)(4*q+m)*128 + r)*8);
      }
      float sA0=qsum4(dot32(ws,xa));
      float sA1=qsum4(dot32(ws,xb));
      float sB0=qsum4(dot32(wh,xa));
      float sB1=qsum4(dot32(wh,xb));
      int phys = i*136 + ((r>>3)^(i&15))*8 + (r&7);
      if      (q==0) sh_sWs16[0][r] = (half_t)sA0;
      else if (q==1) sh_sWs16[1][r] = (half_t)sA1;
      else if (q==2) sh_histWh[0][phys] = (half_t)sB0;
      else           sh_histWh[1][phys] = (half_t)sB1;
    }
    bar();
    if (i > 0){
      // ---- P6: unnormalized probs[l][t] = exp(logit - 4), 2 lanes/(l,t) ----
      {
        int h6=tid&1, t6=(tid>>1)&127, l6=tid>>8;
        if (t6 <= i){
          const half_t* hwrow = &sh_histWh[l6][t6*136];
          const half_t* swrow = &sh_sWs16[l6][64*h6];
          const half_t* vwrow = &sh_vW16[64*h6];
          int key = t6 & 15;
          float s = 0.f;
          #pragma unroll
          for (int m=0;m<8;++m){
            uint4 hw = *reinterpret_cast<const uint4*>(hwrow + (((8*h6+m)^key)*8));
            uint4 sw = *reinterpret_cast<const uint4*>(swrow + 8*m);
            uint4 vw = *reinterpret_cast<const uint4*>(vwrow + 8*m);
            half2_t h2,s2,v2;
            h2=bc2(hw.x); s2=bc2(sw.x); v2=bc2(vw.x);
            s += tanhf_((float)s2[0]+(float)h2[0])*(float)v2[0];
            s += tanhf_((float)s2[1]+(float)h2[1])*(float)v2[1];
            h2=bc2(hw.y); s2=bc2(sw.y); v2=bc2(vw.y);
            s += tanhf_((float)s2[0]+(float)h2[0])*(float)v2[0];
            s += tanhf_((float)s2[1]+(float)h2[1])*(float)v2[1];
            h2=bc2(hw.z); s2=bc2(sw.z); v2=bc2(vw.z);
            s += tanhf_((float)s2[0]+(float)h2[0])*(float)v2[0];
            s += tanhf_((float)s2[1]+(float)h2[1])*(float)v2[1];
            h2=bc2(hw.w); s2=bc2(sw.w); v2=bc2(vw.w);
            s += tanhf_((float)s2[0]+(float)h2[0])*(float)v2[0];
            s += tanhf_((float)s2[1]+(float)h2[1])*(float)v2[1];
          }
          s += qxor1(s);   // pair combine (VALU)
          if (h6==0) sh_probs[l6][t6] = __expf(s - 4.0f);
        } else if ((tid&1)==0){
          sh_probs[tid>>8][(tid>>1)&127] = 0.f;
        }
      }
      bar();
      // ---- P8: ctx + Sum(p) fused; normalize at write ----
      {
        int ts=tid&15, oc=(tid>>4)&15, l8=tid>>8;
        float c0=0.f,c1=0.f,c2=0.f,c3=0.f,c4=0.f,c5=0.f,c6=0.f,c7=0.f, ps=0.f;
        #pragma unroll
        for (int k=0;k<8;++k){
          int t = ts + 16*k;
          float p = sh_probs[l8][t];
          uint4 hv = *reinterpret_cast<const uint4*>(&sh_hist[l8][t*136 + ((oc^(t&15))*8)]);
          half2_t a=bc2(hv.x), e=bc2(hv.y), f=bc2(hv.z), g=bc2(hv.w);
          c0+=p*(float)a[0]; c1+=p*(float)a[1]; c2+=p*(float)e[0]; c3+=p*(float)e[1];
          c4+=p*(float)f[0]; c5+=p*(float)f[1]; c6+=p*(float)g[0]; c7+=p*(float)g[1];
          ps+=p;
        }
        c0+=qxor1(c0); c0+=qxor2(c0);  c1+=qxor1(c1); c1+=qxor2(c1);
        c2+=qxor1(c2); c2+=qxor2(c2);  c3+=qxor1(c3); c3+=qxor2(c3);
        c4+=qxor1(c4); c4+=qxor2(c4);  c5+=qxor1(c5); c5+=qxor2(c5);
        c6+=qxor1(c6); c6+=qxor2(c6);  c7+=qxor1(c7); c7+=qxor2(c7);
        ps+=qxor1(ps); ps+=qxor2(ps);
        half2_t p01={(half_t)c0,(half_t)c1}, p23={(half_t)c2,(half_t)c3};
        half2_t p45={(half_t)c4,(half_t)c5}, p67={(half_t)c6,(half_t)c7};
        p01 = p01 + bcH(__shfl_xor(bcI(p01),4)); p23 = p23 + bcH(__shfl_xor(bcI(p23),4));
        p45 = p45 + bcH(__shfl_xor(bcI(p45),4)); p67 = p67 + bcH(__shfl_xor(bcI(p67),4));
        ps += __shfl_xor(ps,4);
        p01 = p01 + bcH(__shfl_xor(bcI(p01),8)); p23 = p23 + bcH(__shfl_xor(bcI(p23),8));
        p45 = p45 + bcH(__shfl_xor(bcI(p45),8)); p67 = p67 + bcH(__shfl_xor(bcI(p67),8));
        ps += __shfl_xor(ps,8);
        if (ts==0){
          float inv = rcp_f(ps);
          half2_t o01={(half_t)((float)p01[0]*inv),(half_t)((float)p01[1]*inv)};
          half2_t o23={(half_t)((float)p23[0]*inv),(half_t)((float)p23[1]*inv)};
          half2_t o45={(half_t)((float)p45[0]*inv),(half_t)((float)p45[1]*inv)};
          half2_t o67={(half_t)((float)p67[0]*inv),(half_t)((float)p67[1]*inv)};
          *reinterpret_cast<uint4*>(&sh_fc2in[l8][oc*8]) =
              make_uint4((unsigned)bcI(o01),(unsigned)bcI(o23),(unsigned)bcI(o45),(unsigned)bcI(o67));
        }
      }
      bar();
      // ---- P9: h_att[l] = fc2 @ [c|h_raw] + fc2_b (w shared across l) ----
      {
        float e0=0.f, e1=0.f;
        #pragma unroll
        for (int h=0; h<2; ++h){
          uint4 w[4], x0[4], x1[4];
          #pragma unroll
          for (int m=0;m<4;++m){
            int kc = 8*q + 4*h + m;
            w[m]  = *reinterpret_cast<const uint4*>(fc2Pack + ((size_t)kc*128 + r)*8);
            x0[m] = *reinterpret_cast<const uint4*>(&sh_fc2in[0][64*q + 32*h + 8*m]);
            x1[m] = *reinterpret_cast<const uint4*>(&sh_fc2in[1][64*q + 32*h + 8*m]);
          }
          e0 += dot32(w,x0);
          e1 += dot32(w,x1);
        }
        e0 = qsum4(e0); e1 = qsum4(e1);
        if      (q==0){ float v=e0+bF; sh_hatt32[0][r]=v; sh_hatt_pk[0][r]=(half_t)v; }
        else if (q==1){ float v=e1+bF; sh_hatt32[1][r]=v; sh_hatt_pk[1][r]=(half_t)v; }
      }
    } else {
      if (tid < 256){
        int l=tid>>7, row=tid&127;
        float hv = sh_hraw32[l][row];
        sh_hatt32[l][row]=hv; sh_hatt_pk[l][row]=(half_t)hv;
      }
    }
    bar();
  }
}

// Final: out[b,t] = sigmoid(tanh(out_W . [o1[b,t] | o2[b,min(t+10,127)]] + out_b))
__global__ void out_kernel(const half_t* __restrict__ o1h, const half_t* __restrict__ o2h,
                           const float* __restrict__ outW, const float* __restrict__ outb,
                           float* __restrict__ dout){
  int tid = blockIdx.x*blockDim.x + threadIdx.x;
  int q = tid&3, job = tid>>2;
  int b = job>>7, t = job&127;
  int t2 = t+10; if (t2>127) t2=127;
  const half_t* r1 = o1h + (size_t)(b*128+t)*128;
  const half_t* r2 = o2h + (size_t)(b*128+t2)*128;
  float acc=0.f;
  for (int j=q*32; j<q*32+32; ++j) acc += outW[j]*(float)r1[j];
  for (int j=q*32; j<q*32+32; ++j) acc += outW[128+j]*(float)r2[j];
  acc += __shfl_xor(acc,1);
  acc += __shfl_xor(acc,2);
  if (q==0){
    float d = tanhf_(acc + outb[0]);
    dout[job] = rcp_f(1.f+__expf(-d));
  }
}

static inline void launch_pack(const void* src, half_t* dst, int R, int K, int ld,
                               int coloff, int RT, int row_off, hipStream_t s){
  int total = R*K;
  pack_k<<<(total+255)/256, 256, 0, s>>>((const float*)src, dst, R, K, ld, coloff, RT, row_off);
}

extern "C" void kernel_launch(void* const* d_in, const int* in_sizes, int n_in,
                              void* d_out, int out_size, void* d_ws, size_t ws_size,
                              hipStream_t stream) {
  const float* received = (const float*)d_in[0];
  const float* Wih1_0 = (const float*)d_in[1];
  const float* Whh1_0 = (const float*)d_in[2];
  const float* bih1_0 = (const float*)d_in[3];
  const float* bhh1_0 = (const float*)d_in[4];
  const float* Wih1_1 = (const float*)d_in[5];
  const float* Whh1_1 = (const float*)d_in[6];
  const float* bih1_1 = (const float*)d_in[7];
  const float* bhh1_1 = (const float*)d_in[8];
  const float* Wih2_0 = (const float*)d_in[9];
  const float* Whh2_0 = (const float*)d_in[10];
  const float* bih2_0 = (const float*)d_in[11];
  const float* bhh2_0 = (const float*)d_in[12];
  const float* Wih2_1 = (const float*)d_in[13];
  const float* Whh2_1 = (const float*)d_in[14];
  const float* bih2_1 = (const float*)d_in[15];
  const float* bhh2_1 = (const float*)d_in[16];
  const float* attn_W = (const float*)d_in[17];
  const float* v_W    = (const float*)d_in[18];
  const float* fc2_W  = (const float*)d_in[19];
  const float* fc2_b  = (const float*)d_in[20];
  const float* out_W  = (const float*)d_in[21];
  const float* out_b  = (const float*)d_in[22];

  half_t* ws = (half_t*)d_ws;
  half_t* W0pack  = ws + 0;        // 2 x [16][384][8] = 98304
  half_t* W1pack  = ws + 98304;    // 2 x [16][768][8] = 196608
  half_t* WsPack  = ws + 294912;   // [16][128][8] = 16384
  half_t* WhPack  = ws + 311296;   // 16384
  half_t* fc2Pack = ws + 327552;   // [32][128][8] = 32768
  half_t* o1h     = ws + 360448;   // 32*128*128 = 524288
  half_t* o2h     = ws + 884736;   // 524288

  launch_pack(Whh1_0, W0pack,          384, 128, 128, 0, 384, 0, stream);
  launch_pack(Whh2_0, W0pack + 49152,  384, 128, 128, 0, 384, 0, stream);
  launch_pack(Wih1_1, W1pack,          384, 128, 128, 0, 768, 0, stream);
  launch_pack(Whh1_1, W1pack,          384, 128, 128, 0, 768, 384, stream);
  launch_pack(Wih2_1, W1pack + 98304,  384, 128, 128, 0, 768, 0, stream);
  launch_pack(Whh2_1, W1pack + 98304,  384, 128, 128, 0, 768, 384, stream);
  launch_pack(attn_W, WsPack,          128, 128, 256, 0,   128, 0, stream);
  launch_pack(attn_W, WhPack,          128, 128, 256, 128, 128, 0, stream);
  launch_pack(fc2_W,  fc2Pack,         128, 256, 256, 0,   128, 0, stream);

  gru_main<<<64, 512, 0, stream>>>(
      received,
      Wih1_0, Wih2_0,
      bih1_0, bhh1_0, bih1_1, bhh1_1,
      bih2_0, bhh2_0, bih2_1, bhh2_1,
      v_W, fc2_b,
      W0pack, W1pack, WsPack, WhPack, fc2Pack,
      o1h, o2h);

  out_kernel<<<64, 256, 0, stream>>>(o1h, o2h, out_W, out_b, (float*)d_out);
}